// Round 8
// baseline (243.188 us; speedup 1.0000x reference)
//
#include <hip/hip_runtime.h>
#include <cmath>

#define HW (512*512)
#define NSUB 2048            // 64 bins x 32 sub-bins
#define THREADS1 1024
#define BLKS_PER_IMG 32
#define NLCOPY 8             // XCD-affine copies of the global L table

// Phase 1: RGB -> Lab. L channel counts via global atomics (TCC pipe, 8 XCD
// copies); a/b channels via dual wave-parity LDS tables (LDS RMW pipe).
// The two atomic pipes run concurrently.
__global__ __launch_bounds__(THREADS1) void count_kernel(const float* __restrict__ img,
                                                         unsigned* __restrict__ glL,
                                                         unsigned* __restrict__ part) {
    __shared__ unsigned sh[2][2 * NSUB];   // 32 KB: a/b tables, dual parity
    const int tid = threadIdx.x;
    unsigned* flat = &sh[0][0];
    for (int i = tid; i < 4 * NSUB; i += THREADS1) flat[i] = 0u;
    __syncthreads();

    unsigned* h = sh[(tid >> 6) & 1];

    const int b  = blockIdx.y;
    const int bx = blockIdx.x;
    const int blin = bx + b * BLKS_PER_IMG;
    unsigned* gL = glL + ((size_t)b * NLCOPY + (blin & (NLCOPY - 1))) * NSUB;

    const float* base = img + (size_t)b * 3u * HW;

    const int stride = BLKS_PER_IMG * THREADS1 * 4;
    for (int p = (bx * THREADS1 + tid) * 4; p < HW; p += stride) {
        float4 r4 = *reinterpret_cast<const float4*>(base + p);
        float4 g4 = *reinterpret_cast<const float4*>(base + p + HW);
        float4 b4 = *reinterpret_cast<const float4*>(base + p + 2 * HW);
        float rr[4] = {r4.x, r4.y, r4.z, r4.w};
        float gg[4] = {g4.x, g4.y, g4.z, g4.w};
        float bl[4] = {b4.x, b4.y, b4.z, b4.w};

        #pragma unroll
        for (int k = 0; k < 4; ++k) {
            // sRGB -> linear
            float lr = (rr[k] > 0.04045f) ? exp2f(2.4f * log2f((rr[k] + 0.055f) * (1.0f / 1.055f))) : rr[k] * (1.0f / 12.92f);
            float lg = (gg[k] > 0.04045f) ? exp2f(2.4f * log2f((gg[k] + 0.055f) * (1.0f / 1.055f))) : gg[k] * (1.0f / 12.92f);
            float lb = (bl[k] > 0.04045f) ? exp2f(2.4f * log2f((bl[k] + 0.055f) * (1.0f / 1.055f))) : bl[k] * (1.0f / 12.92f);

            // XYZ with xn/zn folded into the matrix rows
            float x = 0.4339530f * lr + 0.3762197f * lg + 0.1898288f * lb;
            float y = 0.2126710f * lr + 0.7151600f * lg + 0.0721690f * lb;
            float z = 0.0177578f * lr + 0.1094766f * lg + 0.8727661f * lb;

            float fx = (x > 0.008856f) ? exp2f(log2f(x) * (1.0f/3.0f)) : 7.787f * x + 16.0f/116.0f;
            float fy = (y > 0.008856f) ? exp2f(log2f(y) * (1.0f/3.0f)) : 7.787f * y + 16.0f/116.0f;
            float fz = (z > 0.008856f) ? exp2f(log2f(z) * (1.0f/3.0f)) : 7.787f * z + 16.0f/116.0f;

            // sub-bin indices (scale/offset folded); ranges provably in [0,2048)
            int iL = (int)(2375.68f    * fy - 327.68f);
            int iA = (int)(4015.6863f  * (fx - fy) + 1028.01569f);
            int iB = (int)(1606.27451f * (fy - fz) + 1028.01569f);

            atomicAdd(gL + iL, 1u);               // global (TCC) pipe
            atomicAdd(&h[iA], 1u);                // LDS pipe
            atomicAdd(&h[NSUB + iB], 1u);
        }
    }
    __syncthreads();

    // a/b: merge dual tables -> per-block partial (plain coalesced stores)
    unsigned* dst = part + (size_t)blin * 2 * NSUB;
    for (int i = tid; i < 2 * NSUB; i += THREADS1) dst[i] = sh[0][i] + sh[1][i];
}

// Phase 2: reduce partials (8 copies for L, 32 block-partials for a/b),
// truncated 204-tap Gaussian conv -> 64 bins, normalize.
__global__ __launch_bounds__(256) void conv_norm_kernel(const unsigned* __restrict__ glL,
                                                        const unsigned* __restrict__ part,
                                                        float* __restrict__ out) {
    __shared__ float sub[NSUB];
    __shared__ float hb[64];
    const int img = blockIdx.x / 3;
    const int ch  = blockIdx.x % 3;
    const int t   = threadIdx.x;

    float acc8[8] = {0,0,0,0,0,0,0,0};
    if (ch == 0) {
        const unsigned* g0 = glL + (size_t)img * NLCOPY * NSUB;
        for (int c = 0; c < NLCOPY; ++c) {
            const unsigned* pc = g0 + (size_t)c * NSUB + t * 8;
            uint4 a = *reinterpret_cast<const uint4*>(pc);
            uint4 d = *reinterpret_cast<const uint4*>(pc + 4);
            acc8[0] += (float)a.x; acc8[1] += (float)a.y;
            acc8[2] += (float)a.z; acc8[3] += (float)a.w;
            acc8[4] += (float)d.x; acc8[5] += (float)d.y;
            acc8[6] += (float)d.z; acc8[7] += (float)d.w;
        }
    } else {
        const unsigned* p0 = part + (size_t)img * BLKS_PER_IMG * 2 * NSUB + (size_t)(ch - 1) * NSUB;
        for (int k = 0; k < BLKS_PER_IMG; ++k) {
            const unsigned* pk = p0 + (size_t)k * 2 * NSUB + t * 8;
            uint4 a = *reinterpret_cast<const uint4*>(pk);
            uint4 d = *reinterpret_cast<const uint4*>(pk + 4);
            acc8[0] += (float)a.x; acc8[1] += (float)a.y;
            acc8[2] += (float)a.z; acc8[3] += (float)a.w;
            acc8[4] += (float)d.x; acc8[5] += (float)d.y;
            acc8[6] += (float)d.z; acc8[7] += (float)d.w;
        }
    }
    #pragma unroll
    for (int i = 0; i < 8; ++i) sub[t * 8 + i] = acc8[i];
    __syncthreads();

    const int j = t >> 2;                  // bin 0..63
    const int q = t & 3;                   // quarter 0..3
    const float C = 2.8853901f;            // 2/ln2
    const float jf = (float)j + 0.5f - (0.5f / 32.0f);
    const int s_lo = 32 * j - 86;          // 204-tap window, 51 per q-lane
    float acc = 0.0f;
    for (int i = 0; i < 51; ++i) {
        int ii = i + j; if (ii >= 51) ii -= 51;   // per-j rotation de-banks lanes
        int s  = s_lo + q + 4 * ii;
        if ((unsigned)s < (unsigned)NSUB) {
            float d = (float)s * (1.0f / 32.0f) - jf;
            acc += sub[s] * exp2f(-C * d * d);
        }
    }
    acc += __shfl_xor(acc, 1, 64);
    acc += __shfl_xor(acc, 2, 64);
    if (q == 0) hb[j] = acc;
    __syncthreads();

    if (t < 64) {
        float v = hb[t];
        float s = v;
        #pragma unroll
        for (int off = 32; off >= 1; off >>= 1) s += __shfl_down(s, off, 64);
        s = __shfl(s, 0, 64);
        out[img * 192 + ch * 64 + t] = v / (s + 1e-8f);
    }
}

extern "C" void kernel_launch(void* const* d_in, const int* in_sizes, int n_in,
                              void* d_out, int out_size, void* d_ws, size_t ws_size,
                              hipStream_t stream) {
    const float* img = (const float*)d_in[0];
    float* out     = (float*)d_out;
    unsigned* glL  = (unsigned*)d_ws;                        // 16*8*2048 u32 = 1 MB
    unsigned* part = glL + (size_t)16 * NLCOPY * NSUB;       // 512 * 2*2048 u32 = 8.4 MB

    const int B = in_sizes[0] / (3 * HW); // 16

    (void)hipMemsetAsync(glL, 0, (size_t)B * NLCOPY * NSUB * sizeof(unsigned), stream);
    count_kernel<<<dim3(BLKS_PER_IMG, B), THREADS1, 0, stream>>>(img, glL, part);
    conv_norm_kernel<<<B * 3, 256, 0, stream>>>(glL, part, out);
}

// Round 9
// 97.011 us; speedup vs baseline: 2.5068x; 2.5068x over previous
//
#include <hip/hip_runtime.h>
#include <cmath>

#define HW (512*512)
#define NSUB 2048            // 64 bins x 32 sub-bins
#define THREADS1 1024
#define BLKS_PER_IMG 32

// Phase 1: RGB -> Lab -> integer sub-bin counting into dual wave-parity LDS
// tables (3 ds_add_u32 per pixel). Per-block partial tables written to ws
// with plain stores (no global atomics).
// Session evidence: LDS-atomic RMW rate is the wall (~5 cy/px); privatization
// layout (R4 16-way, R7 dual, R8 TCC-escape) cannot improve it.
__global__ __launch_bounds__(THREADS1) void count_kernel(const float* __restrict__ img,
                                                         unsigned* __restrict__ part) {
    __shared__ unsigned sh[2][3 * NSUB];   // 48 KB
    const int tid = threadIdx.x;
    unsigned* flat = &sh[0][0];
    for (int i = tid; i < 2 * 3 * NSUB; i += THREADS1) flat[i] = 0u;
    __syncthreads();

    unsigned* h = sh[(tid >> 6) & 1];      // wave parity selects table

    const int b  = blockIdx.y;
    const int bx = blockIdx.x;
    const float* base = img + (size_t)b * 3u * HW;

    const int stride = BLKS_PER_IMG * THREADS1 * 4;
    for (int p = (bx * THREADS1 + tid) * 4; p < HW; p += stride) {
        float4 r4 = *reinterpret_cast<const float4*>(base + p);
        float4 g4 = *reinterpret_cast<const float4*>(base + p + HW);
        float4 b4 = *reinterpret_cast<const float4*>(base + p + 2 * HW);
        float rr[4] = {r4.x, r4.y, r4.z, r4.w};
        float gg[4] = {g4.x, g4.y, g4.z, g4.w};
        float bl[4] = {b4.x, b4.y, b4.z, b4.w};

        #pragma unroll
        for (int k = 0; k < 4; ++k) {
            // sRGB -> linear
            float lr = (rr[k] > 0.04045f) ? exp2f(2.4f * log2f((rr[k] + 0.055f) * (1.0f / 1.055f))) : rr[k] * (1.0f / 12.92f);
            float lg = (gg[k] > 0.04045f) ? exp2f(2.4f * log2f((gg[k] + 0.055f) * (1.0f / 1.055f))) : gg[k] * (1.0f / 12.92f);
            float lb = (bl[k] > 0.04045f) ? exp2f(2.4f * log2f((bl[k] + 0.055f) * (1.0f / 1.055f))) : bl[k] * (1.0f / 12.92f);

            // XYZ with xn/zn folded into the matrix rows
            float x = 0.4339530f * lr + 0.3762197f * lg + 0.1898288f * lb; // x/0.950456
            float y = 0.2126710f * lr + 0.7151600f * lg + 0.0721690f * lb;
            float z = 0.0177578f * lr + 0.1094766f * lg + 0.8727661f * lb; // z/1.088754

            float fx = (x > 0.008856f) ? exp2f(log2f(x) * (1.0f/3.0f)) : 7.787f * x + 16.0f/116.0f;
            float fy = (y > 0.008856f) ? exp2f(log2f(y) * (1.0f/3.0f)) : 7.787f * y + 16.0f/116.0f;
            float fz = (z > 0.008856f) ? exp2f(log2f(z) * (1.0f/3.0f)) : 7.787f * z + 16.0f/116.0f;

            // sub-bin indices (scale/offset folded); ranges provably in [0,2048)
            int iL = (int)(2375.68f    * fy - 327.68f);
            int iA = (int)(4015.6863f  * (fx - fy) + 1028.01569f);
            int iB = (int)(1606.27451f * (fy - fz) + 1028.01569f);

            atomicAdd(&h[iL], 1u);
            atomicAdd(&h[NSUB + iA], 1u);
            atomicAdd(&h[2 * NSUB + iB], 1u);
        }
    }
    __syncthreads();

    // merge dual tables -> per-block partial (plain coalesced stores)
    unsigned* dst = part + ((size_t)(b * BLKS_PER_IMG + bx)) * 3 * NSUB;
    for (int i = tid; i < 3 * NSUB; i += THREADS1) dst[i] = sh[0][i] + sh[1][i];
}

// Phase 2: reduce 32 per-block partials, truncated Gaussian conv -> 64 bins,
// normalize. d(s,j) = (s+0.5)/32 - 0.5 - j; keep 204 taps around s* = 32j+15.5.
__global__ __launch_bounds__(256) void conv_norm_kernel(const unsigned* __restrict__ part,
                                                        float* __restrict__ out) {
    __shared__ float sub[NSUB];
    __shared__ float hb[64];
    const int img = blockIdx.x / 3;
    const int ch  = blockIdx.x % 3;
    const int t   = threadIdx.x;

    // each thread reduces 8 consecutive sub-bins across the 32 partials
    const unsigned* p0 = part + (size_t)img * BLKS_PER_IMG * 3 * NSUB + (size_t)ch * NSUB;
    float acc8[8] = {0,0,0,0,0,0,0,0};
    for (int k = 0; k < BLKS_PER_IMG; ++k) {
        const unsigned* pk = p0 + (size_t)k * 3 * NSUB + t * 8;
        uint4 a = *reinterpret_cast<const uint4*>(pk);
        uint4 c = *reinterpret_cast<const uint4*>(pk + 4);
        acc8[0] += (float)a.x; acc8[1] += (float)a.y;
        acc8[2] += (float)a.z; acc8[3] += (float)a.w;
        acc8[4] += (float)c.x; acc8[5] += (float)c.y;
        acc8[6] += (float)c.z; acc8[7] += (float)c.w;
    }
    #pragma unroll
    for (int i = 0; i < 8; ++i) sub[t * 8 + i] = acc8[i];
    __syncthreads();

    const int j = t >> 2;                  // bin 0..63
    const int q = t & 3;                   // quarter 0..3
    const float C = 2.8853901f;            // 2/ln2
    const float jf = (float)j + 0.5f - (0.5f / 32.0f);
    const int s_lo = 32 * j - 86;          // 204-tap window, 51 per q-lane
    float acc = 0.0f;
    for (int i = 0; i < 51; ++i) {
        int ii = i + j; if (ii >= 51) ii -= 51;   // per-j rotation de-banks lanes
        int s  = s_lo + q + 4 * ii;
        if ((unsigned)s < (unsigned)NSUB) {
            float d = (float)s * (1.0f / 32.0f) - jf;
            acc += sub[s] * exp2f(-C * d * d);
        }
    }
    acc += __shfl_xor(acc, 1, 64);
    acc += __shfl_xor(acc, 2, 64);
    if (q == 0) hb[j] = acc;
    __syncthreads();

    if (t < 64) {
        float v = hb[t];
        float s = v;
        #pragma unroll
        for (int off = 32; off >= 1; off >>= 1) s += __shfl_down(s, off, 64);
        s = __shfl(s, 0, 64);
        out[img * 192 + ch * 64 + t] = v / (s + 1e-8f);
    }
}

extern "C" void kernel_launch(void* const* d_in, const int* in_sizes, int n_in,
                              void* d_out, int out_size, void* d_ws, size_t ws_size,
                              hipStream_t stream) {
    const float* img = (const float*)d_in[0];
    float* out     = (float*)d_out;
    unsigned* part = (unsigned*)d_ws;     // 16*32 blocks * 3*2048 u32 = 12.6 MB

    const int B = in_sizes[0] / (3 * HW); // 16

    count_kernel<<<dim3(BLKS_PER_IMG, B), THREADS1, 0, stream>>>(img, part);
    conv_norm_kernel<<<B * 3, 256, 0, stream>>>(part, out);
}